// Round 11
// baseline (674.145 us; speedup 1.0000x reference)
//
#include <hip/hip_runtime.h>
#include <math.h>

#define TPB 256
#define SCAN_ITEMS 4
#define SCAN_BLOCK (TPB * SCAN_ITEMS)
#define TIECAP 2048
#define HIST_BLOCKS 104
#define BW 512                // bucket width in vertices (2^9)
#define BUCKET_BLOCKS 256     // contiguous chunk per block keeps bucket ranges dense
#define BIG 1024              // big block for latency-bound scatter/gather kernels

#define FLAG_AGG  (1ull << 62)
#define FLAG_PRE  (2ull << 62)
#define FLAG_MASK (3ull << 62)

// ---------------- block-wide exclusive scan helper (256 threads = 4 waves) ----
static __device__ __forceinline__ int block_scan_excl(int v, int* lds, int& total)
{
    int lane = threadIdx.x & 63;
    int wid  = threadIdx.x >> 6;
    int x = v;
#pragma unroll
    for (int off = 1; off < 64; off <<= 1) {
        int y = __shfl_up(x, off, 64);
        if (lane >= off) x += y;
    }
    if (lane == 63) lds[wid] = x;
    __syncthreads();
    int t0 = lds[0], t1 = lds[1], t2 = lds[2], t3 = lds[3];
    int wOff = (wid > 0 ? t0 : 0) + (wid > 1 ? t1 : 0) + (wid > 2 ? t2 : 0);
    total = t0 + t1 + t2 + t3;
    __syncthreads();
    return wOff + x - v;   // exclusive prefix of this thread's value
}

// ---------------- init: zero hist + state + cursors + lookback descs -------
__global__ void k_init(unsigned* hist, unsigned* state, int k,
                       unsigned* cursor, int NB, int CAP,
                       unsigned long long* desc, int nTiles)
{
    int i = threadIdx.x;
    for (int j = i; j < 256; j += blockDim.x) hist[j] = 0u;
    if (cursor) {
        for (int j = i; j < NB; j += blockDim.x)
            cursor[j * 16] = (unsigned)(j * CAP);   // 64B-padded cursors
    }
    for (int j = i; j < nTiles; j += blockDim.x) desc[j] = 0ull;  // INVALID
    if (i == 0) {
        state[0] = 0u;            // prefix
        state[1] = (unsigned)k;   // kk remaining
        state[2] = 0u;            // T
        state[3] = 0u;            // tie count
        state[4] = 0u;            // nValid
    }
}

// ---------------- per-vertex dot products (wave per vertex) ----------------
__global__ void k_dots(const float* __restrict__ verts,
                       const float* __restrict__ w0, const float* __restrict__ b0,
                       const float* __restrict__ w1, const float* __restrict__ b1,
                       long long* __restrict__ iacc, long long* __restrict__ s1q, int V)
{
    int gid  = blockIdx.x * blockDim.x + threadIdx.x;
    int v    = gid >> 6;
    int lane = gid & 63;
    if (v >= V) return;
    const float2 a  = ((const float2*)(verts + (size_t)v * 128))[lane];
    const float2 wa = ((const float2*)w0)[lane];
    const float2 wb = ((const float2*)w1)[lane];
    float p0 = a.x * wa.x + a.y * wa.y;
    float p1 = a.x * wb.x + a.y * wb.y;
#pragma unroll
    for (int off = 32; off > 0; off >>= 1) {
        p0 += __shfl_down(p0, off, 64);
        p1 += __shfl_down(p1, off, 64);
    }
    if (lane == 0) {
        double s0 = (double)p0 + (double)b0[0];
        double s1 = (double)p1 + (double)b1[0];
        iacc[v] = (long long)llrint(s0 * 1099511627776.0);   // 2^40 fixed point
        s1q[v]  = (long long)llrint(s1 * 1099511627776.0);
    }
}

// ---------------- fallback edge scatter (device atomics) -------------------
__global__ void k_scatter(const int2* __restrict__ edges, const long long* __restrict__ s1q,
                          unsigned long long* __restrict__ iacc, int E)
{
    int i = blockIdx.x * blockDim.x + threadIdx.x;
    if (i >= E) return;
    int2 e = edges[i];
    atomicAdd(&iacc[e.x], (unsigned long long)s1q[e.y]);
    atomicAdd(&iacc[e.y], (unsigned long long)s1q[e.x]);
}

// ---------------- phase 1: bucket the 2E endpoint updates ------------------
__global__ void __launch_bounds__(BIG)
k_bucket(const int2* __restrict__ edges, unsigned* __restrict__ bdata,
         unsigned* __restrict__ cursor, int E, int NB, int CAP, int chunk)
{
    __shared__ unsigned cnt[256];
    __shared__ unsigned base[256];
    const int tid   = threadIdx.x;
    const int start = blockIdx.x * chunk;
    const int end   = min(E, start + chunk);
    for (int j = tid; j < 256; j += BIG) cnt[j] = 0u;
    __syncthreads();
    for (int i = start + tid; i < end; i += BIG) {
        int2 e = edges[i];
        atomicAdd(&cnt[e.x >> 9], 1u);
        atomicAdd(&cnt[e.y >> 9], 1u);
    }
    __syncthreads();
    if (tid < NB) {
        unsigned c = cnt[tid];
        base[tid] = c ? atomicAdd(&cursor[tid * 16], c) : 0u;
        cnt[tid] = 0u;
    }
    __syncthreads();
    for (int i = start + tid; i < end; i += BIG) {
        int2 e = edges[i];
        int b0 = e.x >> 9;
        unsigned p0 = base[b0] + atomicAdd(&cnt[b0], 1u);
        if (p0 < (unsigned)(b0 + 1) * (unsigned)CAP)
            bdata[p0] = ((unsigned)e.y << 9) | (unsigned)(e.x & 511);
        int b1 = e.y >> 9;
        unsigned p1 = base[b1] + atomicAdd(&cnt[b1], 1u);
        if (p1 < (unsigned)(b1 + 1) * (unsigned)CAP)
            bdata[p1] = ((unsigned)e.x << 9) | (unsigned)(e.y & 511);
    }
}

// ---------------- phase 2: per-bucket sum + finalize + hist round 0 --------
__global__ void __launch_bounds__(BIG)
k_bucket_sum(const unsigned* __restrict__ bdata, const unsigned* __restrict__ cursor,
             const long long* __restrict__ s1q, const long long* __restrict__ iacc,
             float* __restrict__ attnf, unsigned* __restrict__ keys,
             unsigned* __restrict__ hist, int V, int CAP)
{
    __shared__ unsigned long long acc[BW];
    __shared__ unsigned lh[256];
    const int b   = blockIdx.x;
    const int tid = threadIdx.x;
    for (int j = tid; j < BW;  j += BIG) acc[j] = 0ull;
    for (int j = tid; j < 256; j += BIG) lh[j] = 0u;
    __syncthreads();
    unsigned n = cursor[b * 16] - (unsigned)(b * CAP);
    if (n > (unsigned)CAP) n = (unsigned)CAP;
    const unsigned* src = bdata + (size_t)b * CAP;
    for (unsigned i = tid; i < n; i += BIG) {
        unsigned p = src[i];
        atomicAdd(&acc[p & 511u], (unsigned long long)s1q[p >> 9]);
    }
    __syncthreads();
    for (int j = tid; j < BW; j += BIG) {
        int v = b * BW + j;
        if (v < V) {
            long long tot = iacc[v] + (long long)acc[j];
            float a = (float)((double)tot * 9.094947017729282379150390625e-13); // 2^-40
            attnf[v] = a;
            unsigned u = __float_as_uint(a);
            unsigned key = (u & 0x80000000u) ? ~u : (u | 0x80000000u);
            keys[v] = key;
            atomicAdd(&lh[key >> 24], 1u);   // radix round 0 (shift=24)
        }
    }
    __syncthreads();
    for (int j = tid; j < 256; j += BIG) {
        unsigned c = lh[j];
        if (c) atomicAdd(&hist[j], c);
    }
}

// ---------------- fixed point -> float attn + sortable key (fallback) ------
__global__ void k_finalize(const long long* __restrict__ iacc, float* __restrict__ attnf,
                           unsigned* __restrict__ keys, int V)
{
    int i = blockIdx.x * blockDim.x + threadIdx.x;
    if (i >= V) return;
    float a = (float)((double)iacc[i] * 9.094947017729282379150390625e-13); // 2^-40
    attnf[i] = a;
    unsigned u = __float_as_uint(a);
    keys[i] = (u & 0x80000000u) ? ~u : (u | 0x80000000u);
}

// ---------------- radix round-0 histogram (fallback path only) -------------
__global__ void k_hist(const unsigned* __restrict__ keys, int V, unsigned* __restrict__ hist)
{
    __shared__ unsigned lh[256];
    lh[threadIdx.x] = 0u;      // TPB == 256
    __syncthreads();
    int stride = gridDim.x * blockDim.x;
    for (int i = blockIdx.x * blockDim.x + threadIdx.x; i < V; i += stride)
        atomicAdd(&lh[keys[i] >> 24], 1u);
    __syncthreads();
    unsigned c = lh[threadIdx.x];
    if (c) atomicAdd(&hist[threadIdx.x], c);
}

// ---------------- fused radix select: round-0 select + rounds 1-3 ----------
// Single block; keys (V*4B) are L2-resident after the hist pass.
__global__ void __launch_bounds__(BIG)
k_radix_tail(const unsigned* __restrict__ keys, int V,
             const unsigned* __restrict__ hist0, unsigned* __restrict__ state)
{
    __shared__ unsigned lh[256];
    __shared__ unsigned spref, skk;
    const int tid = threadIdx.x;
    if (tid == 0) {
        unsigned kk = state[1];
        unsigned cum = 0; int j = 255;
        for (; j > 0; --j) { unsigned c = hist0[j]; if (cum + c >= kk) break; cum += c; }
        spref = ((unsigned)j) << 24;
        skk = kk - cum;
    }
    __syncthreads();
    for (int shift = 16; shift >= 0; shift -= 8) {
        for (int j = tid; j < 256; j += BIG) lh[j] = 0u;
        __syncthreads();
        const unsigned prefHi = spref >> (shift + 8);
        for (int i = tid; i < V; i += BIG) {
            unsigned key = keys[i];
            if ((key >> (shift + 8)) == prefHi)
                atomicAdd(&lh[(key >> shift) & 255u], 1u);
        }
        __syncthreads();
        if (tid == 0) {
            unsigned kk = skk;
            unsigned cum = 0; int j = 255;
            for (; j > 0; --j) { unsigned c = lh[j]; if (cum + c >= kk) break; cum += c; }
            spref |= ((unsigned)j) << shift;
            skk = kk - cum;
        }
        __syncthreads();
    }
    if (tid == 0) {
        state[0] = spref;
        state[1] = skk;       // ties still to select
        state[2] = spref;     // threshold key T
    }
}

// ---------------- fused: mark key>T + collect ties + block totals ----------
__global__ void k_mark(const unsigned* __restrict__ keys, int V,
                       unsigned* __restrict__ state, int* __restrict__ selFlag,
                       int* __restrict__ tieList, unsigned* __restrict__ bsums)
{
    __shared__ int lds[4];
    const unsigned T = state[2];
    int base = blockIdx.x * SCAN_BLOCK + threadIdx.x * SCAN_ITEMS;
    int f[4] = {0, 0, 0, 0};
    unsigned kv[4];
    bool full = (base + 3 < V);
    if (full) {
        uint4 q = *(const uint4*)(keys + base);
        kv[0] = q.x; kv[1] = q.y; kv[2] = q.z; kv[3] = q.w;
    } else {
#pragma unroll
        for (int t = 0; t < 4; ++t)
            kv[t] = (base + t < V) ? keys[base + t] : 0u;
    }
#pragma unroll
    for (int t = 0; t < 4; ++t) {
        if (base + t < V) {
            f[t] = kv[t] > T ? 1 : 0;
            if (kv[t] == T) {
                unsigned p = atomicAdd(&state[3], 1u);
                if (p < TIECAP) tieList[p] = base + t;
            }
        }
    }
    if (full) {
        *(int4*)(selFlag + base) = make_int4(f[0], f[1], f[2], f[3]);
    } else {
#pragma unroll
        for (int t = 0; t < 4; ++t)
            if (base + t < V) selFlag[base + t] = f[t];
    }
    int tot;
    block_scan_excl(f[0] + f[1] + f[2] + f[3], lds, tot);
    if (threadIdx.x == 0) bsums[blockIdx.x] = (unsigned)tot;
}

// ---------------- fused: tie resolve + bsumsV scan (single block) ----------
__global__ void k_vfinish(const unsigned* __restrict__ state,
                          const int* __restrict__ tieList, int* __restrict__ selFlag,
                          unsigned* __restrict__ bsums, int nb)
{
    __shared__ int s[TIECAP];
    __shared__ int lds[4];
    int n  = (int)state[3];
    if (n > TIECAP) n = TIECAP;
    int kk = (int)state[1];
    int tid = threadIdx.x;
    if (kk >= n) {
        for (int i = tid; i < n; i += blockDim.x) {
            int v = tieList[i];
            selFlag[v] = 1;
            atomicAdd(&bsums[v / SCAN_BLOCK], 1u);
        }
    } else {
        for (int i = tid; i < n; i += blockDim.x) s[i] = tieList[i];
        __syncthreads();
        for (int i = tid; i < n; i += blockDim.x) {
            int v = s[i];
            int r = 0;
            for (int j = 0; j < n; ++j) r += (s[j] < v);
            if (r < kk) {
                selFlag[v] = 1;
                atomicAdd(&bsums[v / SCAN_BLOCK], 1u);
            }
        }
    }
    __syncthreads();
    // exclusive scan over bsums (counts -> prefixes)
    int running = 0;
    for (int base = 0; base < nb; base += TPB) {
        int i = base + tid;
        int v = (i < nb) ? (int)bsums[i] : 0;
        int tot;
        int ex = block_scan_excl(v, lds, tot);
        if (i < nb) bsums[i] = (unsigned)(ex + running);
        running += tot;
    }
}

// ---------------- scan over V: pass C (write mask / selIdx / O2) ------------
__global__ void k_scanC_V(const int* __restrict__ selFlag, int V,
                          const unsigned* __restrict__ bsums,
                          int* __restrict__ mask, int* __restrict__ selIdx,
                          const int* __restrict__ vidx_in, float* __restrict__ O2)
{
    __shared__ int lds[4];
    int base = blockIdx.x * SCAN_BLOCK + threadIdx.x * SCAN_ITEMS;
    int f[4] = {0, 0, 0, 0};
    if (base + 3 < V) {
        int4 q = *(const int4*)(selFlag + base);
        f[0] = q.x; f[1] = q.y; f[2] = q.z; f[3] = q.w;
    } else {
#pragma unroll
        for (int t = 0; t < 4; ++t)
            if (base + t < V) f[t] = selFlag[base + t];
    }
    int tot;
    int run = block_scan_excl(f[0] + f[1] + f[2] + f[3], lds, tot) + (int)bsums[blockIdx.x];
#pragma unroll
    for (int t = 0; t < 4; ++t) {
        int idx = base + t;
        if (idx < V) {
            if (f[t]) {
                mask[idx]    = run;
                selIdx[run]  = idx;
                O2[run]      = (float)vidx_in[run];  // verts_idx[:k]
                run++;
            } else {
                mask[idx] = -1;
            }
        }
    }
}

// ---------------- single-pass E partition: decoupled lookback ---------------
// Valid entries written densely at the global valid-prefix; invalid tail is
// CONSTANT payload, filled by k_tail_E afterwards. Descriptor per tile:
// {flag:2, inclusive/aggregate count:62}, agent-scope atomics.
__global__ void k_part_E(const int* __restrict__ edges, int E, const int* __restrict__ mask,
                         const int* __restrict__ eidx_in,
                         unsigned long long* __restrict__ desc,
                         unsigned* __restrict__ state,
                         float* __restrict__ O1, float* __restrict__ O3,
                         float* __restrict__ O4)
{
    __shared__ int lds[4];
    __shared__ float2 lv[SCAN_BLOCK];
    __shared__ float  le[SCAN_BLOCK];
    __shared__ unsigned sbase;
    const int tile  = blockIdx.x;
    const int start = tile * SCAN_BLOCK;
    const int base  = start + threadIdx.x * SCAN_ITEMS;
    int fl[4] = {0, 0, 0, 0};
    float2 mv[4];
    float  ev[4];
    int s = 0;
#pragma unroll
    for (int t = 0; t < 4; ++t) {
        int i = base + t;
        if (i < E) {
            int2 e = ((const int2*)edges)[i];
            int m0 = mask[e.x], m1 = mask[e.y];
            fl[t] = (m0 >= 0 && m1 >= 0);
            if (fl[t]) {
                mv[t] = make_float2((float)m0, (float)m1);
                ev[t] = (float)eidx_in[i];
            }
            s += fl[t];
        }
    }
    int tot;
    int lrun = block_scan_excl(s, lds, tot);
#pragma unroll
    for (int t = 0; t < 4; ++t) {
        int i = base + t;
        if (i < E && fl[t]) {
            lv[lrun] = mv[t];
            le[lrun] = ev[t];
            lrun++;
        }
    }
    // publish aggregate (tile 0 publishes final prefix immediately)
    if (threadIdx.x == 0) {
        unsigned long long v = (tile == 0 ? FLAG_PRE : FLAG_AGG) | (unsigned long long)(unsigned)tot;
        __hip_atomic_store(&desc[tile], v, __ATOMIC_RELEASE, __HIP_MEMORY_SCOPE_AGENT);
    }
    // wave 0: windowed lookback over predecessors
    if (threadIdx.x < 64) {
        unsigned run = 0;
        if (tile > 0) {
            int j = tile - 1;
            while (true) {
                int idx = j - (int)threadIdx.x;
                unsigned long long d = 0ull;
                if (idx >= 0)
                    d = __hip_atomic_load(&desc[idx], __ATOMIC_ACQUIRE, __HIP_MEMORY_SCOPE_AGENT);
                unsigned long long fbits = d & FLAG_MASK;
                bool isPre = (idx >= 0) && (fbits == FLAG_PRE);
                bool isInv = (idx >= 0) && (fbits == 0ull);
                unsigned long long bPre = __ballot(isPre);
                unsigned long long bInv = __ballot(isInv);
                int firstPre = bPre ? (__ffsll((long long)bPre) - 1) : 64;
                int firstInv = bInv ? (__ffsll((long long)bInv) - 1) : 64;
                if (firstInv < firstPre) continue;   // stale window: retry
                unsigned contrib = 0;
                if (idx >= 0 && (int)threadIdx.x <= firstPre)
                    contrib = (unsigned)(d & ~FLAG_MASK);
#pragma unroll
                for (int off = 32; off > 0; off >>= 1)
                    contrib += __shfl_down(contrib, off, 64);
                contrib = __shfl(contrib, 0, 64);
                run += contrib;
                if (firstPre < 64) break;
                j -= 64;
            }
        }
        if (threadIdx.x == 0) {
            sbase = run;
            __hip_atomic_store(&desc[tile],
                               FLAG_PRE | (unsigned long long)(unsigned)(run + tot),
                               __ATOMIC_RELEASE, __HIP_MEMORY_SCOPE_AGENT);
            if (tile == (int)gridDim.x - 1) {
                state[4] = run + (unsigned)tot;     // nValid
                *O4 = (float)(run + (unsigned)tot); // n_edges output
            }
        }
    }
    __syncthreads();
    const unsigned vstart = sbase;
    for (int j = threadIdx.x; j < tot; j += TPB) {
        ((float2*)O1)[vstart + j] = lv[j];
        O3[vstart + j] = le[j];
    }
}

// ---------------- fill invalid tail [nValid, E) with constant -1 ------------
__global__ void k_tail_E(const unsigned* __restrict__ state, int E,
                         float* __restrict__ O1, float* __restrict__ O3)
{
    __shared__ unsigned nv;
    if (threadIdx.x == 0) nv = state[4];
    __syncthreads();
    int i = blockIdx.x * blockDim.x + threadIdx.x;
    if (i >= E || i < (int)nv) return;
    ((float2*)O1)[i] = make_float2(-1.0f, -1.0f);
    O3[i] = -1.0f;
}

// ---------------- gather + tanh scale: verts_up -----------------------------
__global__ void k_verts_up(const float* __restrict__ verts, const int* __restrict__ selIdx,
                           const float* __restrict__ attnf, float* __restrict__ O0, int k)
{
    int idx = blockIdx.x * blockDim.x + threadIdx.x;
    if (idx >= k * 32) return;
    int r = idx >> 5;
    int c = idx & 31;
    int v = selIdx[r];
    float t = tanhf(attnf[v]);
    float4 x = ((const float4*)verts)[(size_t)v * 32 + c];
    x.x *= t; x.y *= t; x.z *= t; x.w *= t;
    ((float4*)O0)[(size_t)r * 32 + c] = x;
}

// ============================ host launcher ================================
extern "C" void kernel_launch(void* const* d_in, const int* in_sizes, int n_in,
                              void* d_out, int out_size, void* d_ws, size_t ws_size,
                              hipStream_t stream)
{
    const float* verts = (const float*)d_in[0];
    const int*   edges = (const int*)d_in[1];
    const int*   vidx  = (const int*)d_in[2];
    const int*   eidx  = (const int*)d_in[3];
    const float* w0w   = (const float*)d_in[4];
    const float* w0b   = (const float*)d_in[5];
    const float* w1w   = (const float*)d_in[6];
    const float* w1b   = (const float*)d_in[7];

    const int V = in_sizes[2];
    const int E = in_sizes[3];
    const int F = in_sizes[0] / V;            // 128
    const int k = (int)((double)V * 0.8);     // matches python int(nv*RATIO)

    // ---- workspace carve-up ----
    char* p = (char*)d_ws;
    auto alloc = [&](size_t bytes) -> char* {
        char* r = p;
        p += (bytes + 255) & ~(size_t)255;
        return r;
    };
    long long* iacc   = (long long*)alloc((size_t)V * 8);
    long long* s1q    = (long long*)alloc((size_t)V * 8);
    float*     attnf  = (float*)alloc((size_t)V * 4);
    unsigned*  keys   = (unsigned*)alloc((size_t)V * 4);
    int*       selFlag= (int*)alloc((size_t)V * 4);
    int*       mask   = (int*)alloc((size_t)V * 4);
    int*       selIdx = (int*)alloc((size_t)k * 4);
    int*       tieList= (int*)alloc((size_t)TIECAP * 4);
    unsigned*  hist   = (unsigned*)alloc(256 * 4);
    unsigned*  state  = (unsigned*)alloc(64);
    const int nbV = (V + SCAN_BLOCK - 1) / SCAN_BLOCK;
    const int nbE = (E + SCAN_BLOCK - 1) / SCAN_BLOCK;
    unsigned*  bsumsV = (unsigned*)alloc((size_t)nbV * 4);
    unsigned long long* desc = (unsigned long long*)alloc((size_t)nbE * 8);

    // bucket-aggregation scratch (falls back to atomic scatter if ws too small)
    const int NB  = (V + BW - 1) / BW;
    long long avgc = (2LL * E * BW) / (V > 0 ? V : 1);
    const int CAP = (int)(avgc + avgc / 8 + 1024);   // mean + 12.5% + 1024 (~28 sigma)
    unsigned*  cursor = (unsigned*)alloc(256 * 64);              // 64B-padded
    unsigned*  bdata  = (unsigned*)alloc((size_t)NB * CAP * 4);  // 4B packed elems
    const bool useBucket = (NB <= 256) && (V < (1 << 17)) &&
                           ((size_t)(p - (char*)d_ws) <= ws_size);

    // ---- output carve-up (all written as float values) ----
    float* out = (float*)d_out;
    float* O0 = out;                         // verts_up   k*F
    float* O1 = O0 + (size_t)k * F;          // new_edges  E*2
    float* O2 = O1 + (size_t)E * 2;          // verts_idx  k
    float* O3 = O2 + (size_t)k;              // edges_idx  E
    float* O4 = O3 + (size_t)E;              // n_edges    1

    k_init<<<1, TPB, 0, stream>>>(hist, state, k,
                                  useBucket ? cursor : nullptr, NB, CAP, desc, nbE);

    k_dots<<<(int)(((size_t)V * 64 + TPB - 1) / TPB), TPB, 0, stream>>>(
        verts, w0w, w0b, w1w, w1b, iacc, s1q, V);

    if (useBucket) {
        const int chunk = (E + BUCKET_BLOCKS - 1) / BUCKET_BLOCKS;
        k_bucket<<<BUCKET_BLOCKS, BIG, 0, stream>>>(
            (const int2*)edges, bdata, cursor, E, NB, CAP, chunk);
        k_bucket_sum<<<NB, BIG, 0, stream>>>(
            bdata, cursor, s1q, iacc, attnf, keys, hist, V, CAP);
    } else {
        k_scatter<<<(E + TPB - 1) / TPB, TPB, 0, stream>>>(
            (const int2*)edges, s1q, (unsigned long long*)iacc, E);
        k_finalize<<<(V + TPB - 1) / TPB, TPB, 0, stream>>>(iacc, attnf, keys, V);
        k_hist<<<HIST_BLOCKS, TPB, 0, stream>>>(keys, V, hist);
    }

    k_radix_tail<<<1, BIG, 0, stream>>>(keys, V, hist, state);

    k_mark<<<nbV, TPB, 0, stream>>>(keys, V, state, selFlag, tieList, bsumsV);
    k_vfinish<<<1, TPB, 0, stream>>>(state, tieList, selFlag, bsumsV, nbV);
    k_scanC_V<<<nbV, TPB, 0, stream>>>(selFlag, V, bsumsV, mask, selIdx, vidx, O2);

    k_part_E<<<nbE, TPB, 0, stream>>>(edges, E, mask, eidx, desc, state, O1, O3, O4);
    k_tail_E<<<(E + BIG - 1) / BIG, BIG, 0, stream>>>(state, E, O1, O3);

    k_verts_up<<<(k * 32 + TPB - 1) / TPB, TPB, 0, stream>>>(verts, selIdx, attnf, O0, k);
}

// Round 12
// 421.148 us; speedup vs baseline: 1.6007x; 1.6007x over previous
//
#include <hip/hip_runtime.h>
#include <math.h>

#define TPB 256
#define SCAN_ITEMS 4
#define SCAN_BLOCK (TPB * SCAN_ITEMS)
#define TIECAP 2048
#define HIST_BLOCKS 104
#define BW 512                // bucket width in vertices (2^9)
#define BUCKET_BLOCKS 256     // contiguous chunk per block keeps bucket ranges dense
#define BIG 1024              // big block for latency-bound scatter/gather kernels

// ---------------- block-wide exclusive scan helper (256 threads = 4 waves) ----
static __device__ __forceinline__ int block_scan_excl(int v, int* lds, int& total)
{
    int lane = threadIdx.x & 63;
    int wid  = threadIdx.x >> 6;
    int x = v;
#pragma unroll
    for (int off = 1; off < 64; off <<= 1) {
        int y = __shfl_up(x, off, 64);
        if (lane >= off) x += y;
    }
    if (lane == 63) lds[wid] = x;
    __syncthreads();
    int t0 = lds[0], t1 = lds[1], t2 = lds[2], t3 = lds[3];
    int wOff = (wid > 0 ? t0 : 0) + (wid > 1 ? t1 : 0) + (wid > 2 ? t2 : 0);
    total = t0 + t1 + t2 + t3;
    __syncthreads();
    return wOff + x - v;   // exclusive prefix of this thread's value
}

// ---------------- init: zero hist + state + bucket cursors -----------------
__global__ void k_init(unsigned* hist, unsigned* state, int k,
                       unsigned* cursor, int NB, int CAP)
{
    int i = threadIdx.x;
    for (int j = i; j < 256; j += blockDim.x) hist[j] = 0u;
    if (cursor) {
        for (int j = i; j < NB; j += blockDim.x)
            cursor[j * 16] = (unsigned)(j * CAP);   // 64B-padded cursors
    }
    if (i == 0) {
        state[0] = 0u;            // prefix
        state[1] = (unsigned)k;   // kk remaining
        state[2] = 0u;            // T
        state[3] = 0u;            // tie count
        state[4] = 0u;            // nValid
    }
}

// ---------------- per-vertex dot products (wave per vertex) ----------------
__global__ void k_dots(const float* __restrict__ verts,
                       const float* __restrict__ w0, const float* __restrict__ b0,
                       const float* __restrict__ w1, const float* __restrict__ b1,
                       long long* __restrict__ iacc, long long* __restrict__ s1q, int V)
{
    int gid  = blockIdx.x * blockDim.x + threadIdx.x;
    int v    = gid >> 6;
    int lane = gid & 63;
    if (v >= V) return;
    const float2 a  = ((const float2*)(verts + (size_t)v * 128))[lane];
    const float2 wa = ((const float2*)w0)[lane];
    const float2 wb = ((const float2*)w1)[lane];
    float p0 = a.x * wa.x + a.y * wa.y;
    float p1 = a.x * wb.x + a.y * wb.y;
#pragma unroll
    for (int off = 32; off > 0; off >>= 1) {
        p0 += __shfl_down(p0, off, 64);
        p1 += __shfl_down(p1, off, 64);
    }
    if (lane == 0) {
        double s0 = (double)p0 + (double)b0[0];
        double s1 = (double)p1 + (double)b1[0];
        iacc[v] = (long long)llrint(s0 * 1099511627776.0);   // 2^40 fixed point
        s1q[v]  = (long long)llrint(s1 * 1099511627776.0);
    }
}

// ---------------- fallback edge scatter (device atomics) -------------------
__global__ void k_scatter(const int2* __restrict__ edges, const long long* __restrict__ s1q,
                          unsigned long long* __restrict__ iacc, int E)
{
    int i = blockIdx.x * blockDim.x + threadIdx.x;
    if (i >= E) return;
    int2 e = edges[i];
    atomicAdd(&iacc[e.x], (unsigned long long)s1q[e.y]);
    atomicAdd(&iacc[e.y], (unsigned long long)s1q[e.x]);
}

// ---------------- phase 1: bucket the 2E endpoint updates ------------------
__global__ void __launch_bounds__(BIG)
k_bucket(const int2* __restrict__ edges, unsigned* __restrict__ bdata,
         unsigned* __restrict__ cursor, int E, int NB, int CAP, int chunk)
{
    __shared__ unsigned cnt[256];
    __shared__ unsigned base[256];
    const int tid   = threadIdx.x;
    const int start = blockIdx.x * chunk;
    const int end   = min(E, start + chunk);
    for (int j = tid; j < 256; j += BIG) cnt[j] = 0u;
    __syncthreads();
    for (int i = start + tid; i < end; i += BIG) {
        int2 e = edges[i];
        atomicAdd(&cnt[e.x >> 9], 1u);
        atomicAdd(&cnt[e.y >> 9], 1u);
    }
    __syncthreads();
    if (tid < NB) {
        unsigned c = cnt[tid];
        base[tid] = c ? atomicAdd(&cursor[tid * 16], c) : 0u;
        cnt[tid] = 0u;
    }
    __syncthreads();
    for (int i = start + tid; i < end; i += BIG) {
        int2 e = edges[i];
        int b0 = e.x >> 9;
        unsigned p0 = base[b0] + atomicAdd(&cnt[b0], 1u);
        if (p0 < (unsigned)(b0 + 1) * (unsigned)CAP)
            bdata[p0] = ((unsigned)e.y << 9) | (unsigned)(e.x & 511);
        int b1 = e.y >> 9;
        unsigned p1 = base[b1] + atomicAdd(&cnt[b1], 1u);
        if (p1 < (unsigned)(b1 + 1) * (unsigned)CAP)
            bdata[p1] = ((unsigned)e.x << 9) | (unsigned)(e.y & 511);
    }
}

// ---------------- phase 2: per-bucket sum + finalize + hist round 0 --------
__global__ void __launch_bounds__(BIG)
k_bucket_sum(const unsigned* __restrict__ bdata, const unsigned* __restrict__ cursor,
             const long long* __restrict__ s1q, const long long* __restrict__ iacc,
             float* __restrict__ attnf, unsigned* __restrict__ keys,
             unsigned* __restrict__ hist, int V, int CAP)
{
    __shared__ unsigned long long acc[BW];
    __shared__ unsigned lh[256];
    const int b   = blockIdx.x;
    const int tid = threadIdx.x;
    for (int j = tid; j < BW;  j += BIG) acc[j] = 0ull;
    for (int j = tid; j < 256; j += BIG) lh[j] = 0u;
    __syncthreads();
    unsigned n = cursor[b * 16] - (unsigned)(b * CAP);
    if (n > (unsigned)CAP) n = (unsigned)CAP;
    const unsigned* src = bdata + (size_t)b * CAP;
    for (unsigned i = tid; i < n; i += BIG) {
        unsigned p = src[i];
        atomicAdd(&acc[p & 511u], (unsigned long long)s1q[p >> 9]);
    }
    __syncthreads();
    for (int j = tid; j < BW; j += BIG) {
        int v = b * BW + j;
        if (v < V) {
            long long tot = iacc[v] + (long long)acc[j];
            float a = (float)((double)tot * 9.094947017729282379150390625e-13); // 2^-40
            attnf[v] = a;
            unsigned u = __float_as_uint(a);
            unsigned key = (u & 0x80000000u) ? ~u : (u | 0x80000000u);
            keys[v] = key;
            atomicAdd(&lh[key >> 24], 1u);   // radix round 0 (shift=24)
        }
    }
    __syncthreads();
    for (int j = tid; j < 256; j += BIG) {
        unsigned c = lh[j];
        if (c) atomicAdd(&hist[j], c);
    }
}

// ---------------- fixed point -> float attn + sortable key (fallback) ------
__global__ void k_finalize(const long long* __restrict__ iacc, float* __restrict__ attnf,
                           unsigned* __restrict__ keys, int V)
{
    int i = blockIdx.x * blockDim.x + threadIdx.x;
    if (i >= V) return;
    float a = (float)((double)iacc[i] * 9.094947017729282379150390625e-13); // 2^-40
    attnf[i] = a;
    unsigned u = __float_as_uint(a);
    keys[i] = (u & 0x80000000u) ? ~u : (u | 0x80000000u);
}

// ---------------- radix round-0 histogram (fallback path only) -------------
__global__ void k_hist(const unsigned* __restrict__ keys, int V, unsigned* __restrict__ hist)
{
    __shared__ unsigned lh[256];
    lh[threadIdx.x] = 0u;      // TPB == 256
    __syncthreads();
    int stride = gridDim.x * blockDim.x;
    for (int i = blockIdx.x * blockDim.x + threadIdx.x; i < V; i += stride)
        atomicAdd(&lh[keys[i] >> 24], 1u);
    __syncthreads();
    unsigned c = lh[threadIdx.x];
    if (c) atomicAdd(&hist[threadIdx.x], c);
}

// ---------------- fused radix select: round-0 select + rounds 1-3 ----------
// Single block; keys (V*4B) are L2-resident after the hist pass.
__global__ void __launch_bounds__(BIG)
k_radix_tail(const unsigned* __restrict__ keys, int V,
             const unsigned* __restrict__ hist0, unsigned* __restrict__ state)
{
    __shared__ unsigned lh[256];
    __shared__ unsigned spref, skk;
    const int tid = threadIdx.x;
    if (tid == 0) {
        unsigned kk = state[1];
        unsigned cum = 0; int j = 255;
        for (; j > 0; --j) { unsigned c = hist0[j]; if (cum + c >= kk) break; cum += c; }
        spref = ((unsigned)j) << 24;
        skk = kk - cum;
    }
    __syncthreads();
    for (int shift = 16; shift >= 0; shift -= 8) {
        for (int j = tid; j < 256; j += BIG) lh[j] = 0u;
        __syncthreads();
        const unsigned prefHi = spref >> (shift + 8);
        for (int i = tid; i < V; i += BIG) {
            unsigned key = keys[i];
            if ((key >> (shift + 8)) == prefHi)
                atomicAdd(&lh[(key >> shift) & 255u], 1u);
        }
        __syncthreads();
        if (tid == 0) {
            unsigned kk = skk;
            unsigned cum = 0; int j = 255;
            for (; j > 0; --j) { unsigned c = lh[j]; if (cum + c >= kk) break; cum += c; }
            spref |= ((unsigned)j) << shift;
            skk = kk - cum;
        }
        __syncthreads();
    }
    if (tid == 0) {
        state[0] = spref;
        state[1] = skk;       // ties still to select
        state[2] = spref;     // threshold key T
    }
}

// ---------------- fused: mark key>T + collect ties + block totals ----------
__global__ void k_mark(const unsigned* __restrict__ keys, int V,
                       unsigned* __restrict__ state, int* __restrict__ selFlag,
                       int* __restrict__ tieList, unsigned* __restrict__ bsums)
{
    __shared__ int lds[4];
    const unsigned T = state[2];
    int base = blockIdx.x * SCAN_BLOCK + threadIdx.x * SCAN_ITEMS;
    int f[4] = {0, 0, 0, 0};
    unsigned kv[4];
    bool full = (base + 3 < V);
    if (full) {
        uint4 q = *(const uint4*)(keys + base);
        kv[0] = q.x; kv[1] = q.y; kv[2] = q.z; kv[3] = q.w;
    } else {
#pragma unroll
        for (int t = 0; t < 4; ++t)
            kv[t] = (base + t < V) ? keys[base + t] : 0u;
    }
#pragma unroll
    for (int t = 0; t < 4; ++t) {
        if (base + t < V) {
            f[t] = kv[t] > T ? 1 : 0;
            if (kv[t] == T) {
                unsigned p = atomicAdd(&state[3], 1u);
                if (p < TIECAP) tieList[p] = base + t;
            }
        }
    }
    if (full) {
        *(int4*)(selFlag + base) = make_int4(f[0], f[1], f[2], f[3]);
    } else {
#pragma unroll
        for (int t = 0; t < 4; ++t)
            if (base + t < V) selFlag[base + t] = f[t];
    }
    int tot;
    block_scan_excl(f[0] + f[1] + f[2] + f[3], lds, tot);
    if (threadIdx.x == 0) bsums[blockIdx.x] = (unsigned)tot;
}

// ---------------- fused: tie resolve + bsumsV scan (single block) ----------
__global__ void k_vfinish(const unsigned* __restrict__ state,
                          const int* __restrict__ tieList, int* __restrict__ selFlag,
                          unsigned* __restrict__ bsums, int nb)
{
    __shared__ int s[TIECAP];
    __shared__ int lds[4];
    int n  = (int)state[3];
    if (n > TIECAP) n = TIECAP;
    int kk = (int)state[1];
    int tid = threadIdx.x;
    if (kk >= n) {
        for (int i = tid; i < n; i += blockDim.x) {
            int v = tieList[i];
            selFlag[v] = 1;
            atomicAdd(&bsums[v / SCAN_BLOCK], 1u);
        }
    } else {
        for (int i = tid; i < n; i += blockDim.x) s[i] = tieList[i];
        __syncthreads();
        for (int i = tid; i < n; i += blockDim.x) {
            int v = s[i];
            int r = 0;
            for (int j = 0; j < n; ++j) r += (s[j] < v);
            if (r < kk) {
                selFlag[v] = 1;
                atomicAdd(&bsums[v / SCAN_BLOCK], 1u);
            }
        }
    }
    __syncthreads();
    // exclusive scan over bsums (counts -> prefixes)
    int running = 0;
    for (int base = 0; base < nb; base += TPB) {
        int i = base + tid;
        int v = (i < nb) ? (int)bsums[i] : 0;
        int tot;
        int ex = block_scan_excl(v, lds, tot);
        if (i < nb) bsums[i] = (unsigned)(ex + running);
        running += tot;
    }
}

// ---------------- scan over V: pass C (write mask / selIdx / O2) ------------
__global__ void k_scanC_V(const int* __restrict__ selFlag, int V,
                          const unsigned* __restrict__ bsums,
                          int* __restrict__ mask, int* __restrict__ selIdx,
                          const int* __restrict__ vidx_in, float* __restrict__ O2)
{
    __shared__ int lds[4];
    int base = blockIdx.x * SCAN_BLOCK + threadIdx.x * SCAN_ITEMS;
    int f[4] = {0, 0, 0, 0};
    if (base + 3 < V) {
        int4 q = *(const int4*)(selFlag + base);
        f[0] = q.x; f[1] = q.y; f[2] = q.z; f[3] = q.w;
    } else {
#pragma unroll
        for (int t = 0; t < 4; ++t)
            if (base + t < V) f[t] = selFlag[base + t];
    }
    int tot;
    int run = block_scan_excl(f[0] + f[1] + f[2] + f[3], lds, tot) + (int)bsums[blockIdx.x];
#pragma unroll
    for (int t = 0; t < 4; ++t) {
        int idx = base + t;
        if (idx < V) {
            if (f[t]) {
                mask[idx]    = run;
                selIdx[run]  = idx;
                O2[run]      = (float)vidx_in[run];  // verts_idx[:k]
                run++;
            } else {
                mask[idx] = -1;
            }
        }
    }
}

// ---------------- scan over E: pass A ---------------------------------------
__global__ void k_scanA_E(const int* __restrict__ edges, int E, const int* __restrict__ mask,
                          unsigned* __restrict__ bsums)
{
    __shared__ int lds[4];
    int base = blockIdx.x * SCAN_BLOCK + threadIdx.x * SCAN_ITEMS;
    int s = 0;
    if (base + 3 < E) {
        const int4* e4 = (const int4*)edges;
        int4 q0 = e4[(base >> 1)];
        int4 q1 = e4[(base >> 1) + 1];
        s += (mask[q0.x] >= 0 && mask[q0.y] >= 0);
        s += (mask[q0.z] >= 0 && mask[q0.w] >= 0);
        s += (mask[q1.x] >= 0 && mask[q1.y] >= 0);
        s += (mask[q1.z] >= 0 && mask[q1.w] >= 0);
    } else {
        for (int t = 0; t < 4; ++t) {
            int i = base + t;
            if (i < E) {
                int a = edges[2 * i], b = edges[2 * i + 1];
                s += (mask[a] >= 0 && mask[b] >= 0);
            }
        }
    }
    int tot;
    block_scan_excl(s, lds, tot);
    if (threadIdx.x == 0) bsums[blockIdx.x] = (unsigned)tot;
}

// ---------------- scan pass B: single block over block sums -----------------
__global__ void k_scanB(unsigned* __restrict__ sums, int nb,
                        unsigned* __restrict__ totalOut, float* __restrict__ outF)
{
    __shared__ int lds[4];
    int tid = threadIdx.x;
    int running = 0;
    for (int base = 0; base < nb; base += TPB) {
        int i = base + tid;
        int v = (i < nb) ? (int)sums[i] : 0;
        int tot;
        int ex = block_scan_excl(v, lds, tot);
        if (i < nb) sums[i] = (unsigned)(ex + running);
        running += tot;
    }
    if (tid == 0) {
        if (totalOut) *totalOut = (unsigned)running;
        if (outF)     *outF    = (float)running;
    }
}

// ---------------- scan over E: pass C — LDS-compacted dense writes ----------
__global__ void k_scanC_E(const int* __restrict__ edges, int E, const int* __restrict__ mask,
                          const unsigned* __restrict__ bsums, const unsigned* __restrict__ state,
                          const int* __restrict__ eidx_in,
                          float* __restrict__ O1, float* __restrict__ O3)
{
    __shared__ int lds[4];
    __shared__ float2 lv[SCAN_BLOCK];   // compacted (m0,m1) pairs
    __shared__ float  le[SCAN_BLOCK];   // compacted eidx values
    const int start = blockIdx.x * SCAN_BLOCK;
    const int base  = start + threadIdx.x * SCAN_ITEMS;
    int fl[4] = {0, 0, 0, 0};
    float2 mv[4];
    float  ev[4];
    int s = 0;
#pragma unroll
    for (int t = 0; t < 4; ++t) {
        int i = base + t;
        if (i < E) {
            int2 e = ((const int2*)edges)[i];
            int m0 = mask[e.x], m1 = mask[e.y];
            fl[t] = (m0 >= 0 && m1 >= 0);
            if (fl[t]) {
                mv[t] = make_float2((float)m0, (float)m1);
                ev[t] = (float)eidx_in[i];
            }
            s += fl[t];
        }
    }
    int tot;
    int lrun = block_scan_excl(s, lds, tot);
#pragma unroll
    for (int t = 0; t < 4; ++t) {
        int i = base + t;
        if (i < E && fl[t]) {
            lv[lrun] = mv[t];
            le[lrun] = ev[t];
            lrun++;
        }
    }
    __syncthreads();
    const int items = min(E - start, SCAN_BLOCK);
    const unsigned vstart = bsums[blockIdx.x];
    const unsigned istart = state[4] + (unsigned)start - vstart;   // nValid + invalid prefix
    for (int j = threadIdx.x; j < tot; j += TPB) {
        ((float2*)O1)[vstart + j] = lv[j];
        O3[vstart + j] = le[j];
    }
    const int ninv = items - tot;
    for (int j = threadIdx.x; j < ninv; j += TPB) {
        ((float2*)O1)[istart + j] = make_float2(-1.0f, -1.0f);
        O3[istart + j] = -1.0f;
    }
}

// ---------------- gather + tanh scale: verts_up -----------------------------
__global__ void k_verts_up(const float* __restrict__ verts, const int* __restrict__ selIdx,
                           const float* __restrict__ attnf, float* __restrict__ O0, int k)
{
    int idx = blockIdx.x * blockDim.x + threadIdx.x;
    if (idx >= k * 32) return;
    int r = idx >> 5;
    int c = idx & 31;
    int v = selIdx[r];
    float t = tanhf(attnf[v]);
    float4 x = ((const float4*)verts)[(size_t)v * 32 + c];
    x.x *= t; x.y *= t; x.z *= t; x.w *= t;
    ((float4*)O0)[(size_t)r * 32 + c] = x;
}

// ============================ host launcher ================================
extern "C" void kernel_launch(void* const* d_in, const int* in_sizes, int n_in,
                              void* d_out, int out_size, void* d_ws, size_t ws_size,
                              hipStream_t stream)
{
    const float* verts = (const float*)d_in[0];
    const int*   edges = (const int*)d_in[1];
    const int*   vidx  = (const int*)d_in[2];
    const int*   eidx  = (const int*)d_in[3];
    const float* w0w   = (const float*)d_in[4];
    const float* w0b   = (const float*)d_in[5];
    const float* w1w   = (const float*)d_in[6];
    const float* w1b   = (const float*)d_in[7];

    const int V = in_sizes[2];
    const int E = in_sizes[3];
    const int F = in_sizes[0] / V;            // 128
    const int k = (int)((double)V * 0.8);     // matches python int(nv*RATIO)

    // ---- workspace carve-up ----
    char* p = (char*)d_ws;
    auto alloc = [&](size_t bytes) -> char* {
        char* r = p;
        p += (bytes + 255) & ~(size_t)255;
        return r;
    };
    long long* iacc   = (long long*)alloc((size_t)V * 8);
    long long* s1q    = (long long*)alloc((size_t)V * 8);
    float*     attnf  = (float*)alloc((size_t)V * 4);
    unsigned*  keys   = (unsigned*)alloc((size_t)V * 4);
    int*       selFlag= (int*)alloc((size_t)V * 4);
    int*       mask   = (int*)alloc((size_t)V * 4);
    int*       selIdx = (int*)alloc((size_t)k * 4);
    int*       tieList= (int*)alloc((size_t)TIECAP * 4);
    unsigned*  hist   = (unsigned*)alloc(256 * 4);
    unsigned*  state  = (unsigned*)alloc(64);
    const int nbV = (V + SCAN_BLOCK - 1) / SCAN_BLOCK;
    const int nbE = (E + SCAN_BLOCK - 1) / SCAN_BLOCK;
    unsigned*  bsumsV = (unsigned*)alloc((size_t)nbV * 4);
    unsigned*  bsumsE = (unsigned*)alloc((size_t)nbE * 4);

    // bucket-aggregation scratch (falls back to atomic scatter if ws too small)
    const int NB  = (V + BW - 1) / BW;
    long long avgc = (2LL * E * BW) / (V > 0 ? V : 1);
    const int CAP = (int)(avgc + avgc / 8 + 1024);   // mean + 12.5% + 1024 (~28 sigma)
    unsigned*  cursor = (unsigned*)alloc(256 * 64);              // 64B-padded
    unsigned*  bdata  = (unsigned*)alloc((size_t)NB * CAP * 4);  // 4B packed elems
    const bool useBucket = (NB <= 256) && (V < (1 << 17)) &&
                           ((size_t)(p - (char*)d_ws) <= ws_size);

    // ---- output carve-up (all written as float values) ----
    float* out = (float*)d_out;
    float* O0 = out;                         // verts_up   k*F
    float* O1 = O0 + (size_t)k * F;          // new_edges  E*2
    float* O2 = O1 + (size_t)E * 2;          // verts_idx  k
    float* O3 = O2 + (size_t)k;              // edges_idx  E
    float* O4 = O3 + (size_t)E;              // n_edges    1

    k_init<<<1, TPB, 0, stream>>>(hist, state, k,
                                  useBucket ? cursor : nullptr, NB, CAP);

    k_dots<<<(int)(((size_t)V * 64 + TPB - 1) / TPB), TPB, 0, stream>>>(
        verts, w0w, w0b, w1w, w1b, iacc, s1q, V);

    if (useBucket) {
        const int chunk = (E + BUCKET_BLOCKS - 1) / BUCKET_BLOCKS;
        k_bucket<<<BUCKET_BLOCKS, BIG, 0, stream>>>(
            (const int2*)edges, bdata, cursor, E, NB, CAP, chunk);
        k_bucket_sum<<<NB, BIG, 0, stream>>>(
            bdata, cursor, s1q, iacc, attnf, keys, hist, V, CAP);
    } else {
        k_scatter<<<(E + TPB - 1) / TPB, TPB, 0, stream>>>(
            (const int2*)edges, s1q, (unsigned long long*)iacc, E);
        k_finalize<<<(V + TPB - 1) / TPB, TPB, 0, stream>>>(iacc, attnf, keys, V);
        k_hist<<<HIST_BLOCKS, TPB, 0, stream>>>(keys, V, hist);
    }

    k_radix_tail<<<1, BIG, 0, stream>>>(keys, V, hist, state);

    k_mark<<<nbV, TPB, 0, stream>>>(keys, V, state, selFlag, tieList, bsumsV);
    k_vfinish<<<1, TPB, 0, stream>>>(state, tieList, selFlag, bsumsV, nbV);
    k_scanC_V<<<nbV, TPB, 0, stream>>>(selFlag, V, bsumsV, mask, selIdx, vidx, O2);

    k_scanA_E<<<nbE, TPB, 0, stream>>>(edges, E, mask, bsumsE);
    k_scanB<<<1, TPB, 0, stream>>>(bsumsE, nbE, &state[4], O4);
    k_scanC_E<<<nbE, TPB, 0, stream>>>(edges, E, mask, bsumsE, state, eidx, O1, O3);

    k_verts_up<<<(k * 32 + TPB - 1) / TPB, TPB, 0, stream>>>(verts, selIdx, attnf, O0, k);
}